// Round 1
// baseline (479.240 us; speedup 1.0000x reference)
//
#include <hip/hip_runtime.h>
#include <math.h>

// Problem constants (from reference): B=128, T=200, V=10, F=256.
constexpr int NV = 10;
constexpr int NF = 256;

__global__ __launch_bounds__(256) void graph_emb_kernel(
    const float* __restrict__ end_output,  // (BT, V, F)
    const float* __restrict__ S,           // (BT, V, V)
    const float* __restrict__ mul,         // (V, V)
    const float* __restrict__ bias,        // (V, V)
    const float* __restrict__ means,       // (1, V)
    const float* __restrict__ stds,        // (1, V)
    const float* __restrict__ emb_in,      // (F, F) - only rows 0..9 used
    const float* __restrict__ emb_out,     // (F, F)
    const float* __restrict__ emb3,        // (V, V)
    const float* __restrict__ emb4,        // (V, V)
    float* __restrict__ out_main,          // (BT, V, F)
    float* __restrict__ out_atten)         // (BT, V, V)
{
    __shared__ __attribute__((aligned(16))) float s_embsum[NV * NF]; // emb_in+emb_out rows 0..9
    __shared__ float s_mul[NV * NV];
    __shared__ float s_bias[NV * NV];
    __shared__ float s_means[NV];
    __shared__ float s_stds[NV];
    __shared__ float s_emb3[NV * NV];
    __shared__ float s_emb4[NV * NV];
    __shared__ float s_sym[NV * NV];
    __shared__ float s_ef[NV * NV];
    __shared__ float s_dist[NV * NV];
    __shared__ float s_sp[NV * NV];
    __shared__ int   s_si[NV * NV];
    __shared__ int   s_ei[NV * NV];
    __shared__ int   s_Di[NV];

    const int tid = threadIdx.x;
    const int bt  = blockIdx.x;
    const size_t slab = (size_t)bt * (NV * NF);
    const int g0 = bt * (NV * NV);

    // ---- Phase 0: load tables + symmetrized S ----
    #pragma unroll
    for (int k = 0; k < NV; ++k) {
        int idx = k * 256 + tid;               // 0..2559 ; emb row d = idx/256, col f = idx%256
        s_embsum[idx] = emb_in[idx] + emb_out[idx];
    }
    if (tid < NV * NV) {
        s_mul[tid]  = mul[tid];
        s_bias[tid] = bias[tid];
        s_emb3[tid] = emb3[tid];
        s_emb4[tid] = emb4[tid];
        int i = tid / NV, j = tid % NV;
        float a = S[g0 + tid];
        float b = S[g0 + j * NV + i];
        s_sym[tid] = fminf(a, b);
    }
    if (tid >= 128 && tid < 128 + NV) {
        s_means[tid - 128] = means[tid - 128];
        s_stds[tid - 128]  = stds[tid - 128];
    }
    __syncthreads();

    // ---- Phase 1: GaussianLayer edge features + init FW state; degree bucket ----
    if (tid < NV * NV) {
        int i = tid / NV, c = tid % NV;
        float acc = 0.f;
        #pragma unroll
        for (int j = 0; j < NV; ++j)
            acc += s_sym[i * NV + j] * s_mul[j * NV + c];
        float x = acc + s_bias[tid];
        const float A = sqrtf(2.0f * 3.14159f);
        float z = (x - s_means[c]) / s_stds[c];
        float tmp = expf(-0.5f * z * z) / (A * s_stds[c]);
        float sg = 1.0f / (1.0f + expf(-tmp));
        s_ef[tid]   = tanhf(sg);
        s_dist[tid] = s_sym[tid];
        s_sp[tid]   = 0.f;
    }
    if (tid >= 128 && tid < 128 + NV) {
        int c = tid - 128;
        float d = 0.f;
        #pragma unroll
        for (int i = 0; i < NV; ++i) d += s_sym[i * NV + c];
        int di = (int)d;                        // d in [0,10): truncation == astype(int32)
        s_Di[c] = min(max(di, 0), NV - 1);
    }
    __syncthreads();

    // ---- Phase 2: Floyd-Warshall with update-indicator accumulation ----
    // In-place is safe: at step k, row k and column k are never relaxed
    // (dist >= 0 so dist[i,k]+dist[k,k] >= dist[i,k], strict < fails).
    #pragma unroll
    for (int k = 0; k < NV; ++k) {
        if (tid < NV * NV) {
            int i = tid / NV, j = tid % NV;
            float t = s_dist[i * NV + k] + s_dist[k * NV + j];
            if (t < s_dist[tid]) {              // == (new != dist)
                s_dist[tid] = t;
                s_sp[tid] += s_ef[tid];
            }
        }
        __syncthreads();
    }

    // ---- Phase 3: integer buckets ----
    if (tid < NV * NV) {
        int si = (int)s_dist[tid];              // dist in [0,1) -> 0, keep generic
        int ei = (int)s_sp[tid];                // sp in [0, ~7.7)
        s_si[tid] = min(max(si, 0), NV - 1);
        s_ei[tid] = min(max(ei, 0), NV - 1);
    }
    __syncthreads();

    // ---- Phase 4: atten_bias = sum_j emb3[Si[i,j]] + emb4[Ei[i,j]] ----
    if (tid < NV * NV) {
        int i = tid / NV, c = tid % NV;
        float acc3 = 0.f, acc4 = 0.f;
        #pragma unroll
        for (int j = 0; j < NV; ++j) {
            acc3 += s_emb3[s_si[i * NV + j] * NV + c];
            acc4 += s_emb4[s_ei[i * NV + j] * NV + c];
        }
        out_atten[g0 + tid] = acc4 + acc3;      // Edge_Encoding + Spatial_Encoding
    }

    // ---- Phase 5: stream outputs = end_output + embsum[Di[row]] ----
    const float4* end4 = reinterpret_cast<const float4*>(end_output + slab);
    float4*       out4 = reinterpret_cast<float4*>(out_main + slab);
    const float4* es4  = reinterpret_cast<const float4*>(s_embsum);
    for (int u = tid; u < NV * NF / 4; u += 256) {   // 640 float4 per block
        int row = u >> 6;                       // u / (NF/4)
        int f4  = u & 63;
        float4 e = end4[u];
        float4 s = es4[s_Di[row] * (NF / 4) + f4];
        e.x += s.x; e.y += s.y; e.z += s.z; e.w += s.w;
        out4[u] = e;
    }
}

extern "C" void kernel_launch(void* const* d_in, const int* in_sizes, int n_in,
                              void* d_out, int out_size, void* d_ws, size_t ws_size,
                              hipStream_t stream) {
    const float* end_output = (const float*)d_in[0];
    const float* S          = (const float*)d_in[1];
    const float* mul        = (const float*)d_in[2];
    const float* bias       = (const float*)d_in[3];
    const float* means      = (const float*)d_in[4];
    const float* stds       = (const float*)d_in[5];
    const float* emb_in     = (const float*)d_in[6];
    const float* emb_out    = (const float*)d_in[7];
    const float* emb3       = (const float*)d_in[8];
    const float* emb4       = (const float*)d_in[9];

    float* out_main  = (float*)d_out;
    float* out_atten = out_main + (size_t)in_sizes[0];   // outputs flat, then atten_bias

    const int BT = in_sizes[1] / (NV * NV);              // 25,600

    graph_emb_kernel<<<BT, 256, 0, stream>>>(
        end_output, S, mul, bias, means, stds,
        emb_in, emb_out, emb3, emb4, out_main, out_atten);
}

// Round 2
// 464.390 us; speedup vs baseline: 1.0320x; 1.0320x over previous
//
#include <hip/hip_runtime.h>
#include <math.h>

// Problem constants (from reference): B=128, T=200, V=10, F=256.
constexpr int NV  = 10;
constexpr int NF  = 256;
constexpr int NC  = NV * NV;   // 100 cells per graph
constexpr int GPB = 4;         // graphs per block = 1 per wave (wave64)

// One wave per (b,t) graph: all graph math is wave-synchronous (no barriers).
// Within a wave, LDS write->read ordering is guaranteed by lockstep execution
// plus compiler-inserted lgkmcnt waits (may-alias on s_dist). In-place FW is
// safe intra-step: at step k, reads touch only row-k/col-k cells, which are
// never relaxed at step k (dist >= 0 => t >= dist for those cells).
__global__ __launch_bounds__(256) void graph_emb_fused(
    const float* __restrict__ end_output,  // (BT, V, F)
    const float* __restrict__ S,           // (BT, V, V)
    const float* __restrict__ mul,         // (V, V)
    const float* __restrict__ bias,        // (V, V)
    const float* __restrict__ means,       // (1, V)
    const float* __restrict__ stds,        // (1, V)
    const float* __restrict__ emb_in,      // (F, F) rows 0..9 used
    const float* __restrict__ emb_out,     // (F, F)
    const float* __restrict__ emb3,        // (V, V)
    const float* __restrict__ emb4,        // (V, V)
    float* __restrict__ out_main,          // (BT, V, F)
    float* __restrict__ out_atten,         // (BT, V, V)
    int BT)
{
    __shared__ __attribute__((aligned(16))) float s_embsum[NV * NF];
    __shared__ float s_mul[NC], s_bias[NC], s_emb3[NC], s_emb4[NC];
    __shared__ float s_means[NV], s_stds[NV];
    __shared__ float s_dist[GPB][NC];
    __shared__ int   s_si[GPB][NC];
    __shared__ int   s_ei[GPB][NC];
    __shared__ int   s_Di[GPB][NV];

    const int tid  = threadIdx.x;
    const int wave = tid >> 6;
    const int lane = tid & 63;
    const int gbase = blockIdx.x * GPB;
    const int g     = gbase + wave;

    // ---- Block-wide table staging (barrier 1 of 2) ----
    for (int idx = tid; idx < NV * NF; idx += 256)
        s_embsum[idx] = emb_in[idx] + emb_out[idx];
    if (tid < NC) {
        s_mul[tid]  = mul[tid];
        s_bias[tid] = bias[tid];
        s_emb3[tid] = emb3[tid];
        s_emb4[tid] = emb4[tid];
    }
    if (tid >= 128 && tid < 128 + NV) {
        s_means[tid - 128] = means[tid - 128];
        s_stds[tid - 128]  = stds[tid - 128];
    }
    __syncthreads();

    // ---- Per-wave graph math (no barriers) ----
    if (g < BT) {
        const int g0 = g * NC;
        const int c0 = lane;          // cells 0..63
        const int c1 = 64 + lane;     // cells 64..99 (lane < 36)
        const bool has1 = (lane < 36);
        const int i0 = c0 / NV, j0 = c0 % NV;
        const int i1 = c1 / NV, j1 = c1 % NV;

        // Symmetrize S into s_dist (sym == initial dist)
        s_dist[wave][c0] = fminf(S[g0 + c0], S[g0 + j0 * NV + i0]);
        if (has1)
            s_dist[wave][c1] = fminf(S[g0 + c1], S[g0 + j1 * NV + i1]);

        // GaussianLayer edge features -> registers
        const float A = sqrtf(2.0f * 3.14159f);
        float ef0 = 0.f, ef1 = 0.f, sp0 = 0.f, sp1 = 0.f;
        {
            float acc = 0.f;
            #pragma unroll
            for (int j = 0; j < NV; ++j)
                acc += s_dist[wave][i0 * NV + j] * s_mul[j * NV + j0];
            float x = acc + s_bias[c0];
            float z = (x - s_means[j0]) / s_stds[j0];
            float tmp = expf(-0.5f * z * z) / (A * s_stds[j0]);
            float sg = 1.0f / (1.0f + expf(-tmp));
            ef0 = tanhf(sg);
        }
        if (has1) {
            float acc = 0.f;
            #pragma unroll
            for (int j = 0; j < NV; ++j)
                acc += s_dist[wave][i1 * NV + j] * s_mul[j * NV + j1];
            float x = acc + s_bias[c1];
            float z = (x - s_means[j1]) / s_stds[j1];
            float tmp = expf(-0.5f * z * z) / (A * s_stds[j1]);
            float sg = 1.0f / (1.0f + expf(-tmp));
            ef1 = tanhf(sg);
        }

        // Degree buckets (lanes 0..9), read pre-FW dist (== sym)
        if (lane < NV) {
            float d = 0.f;
            #pragma unroll
            for (int i = 0; i < NV; ++i) d += s_dist[wave][i * NV + lane];
            int di = (int)d;   // d in [0,10): trunc == astype(int32)
            s_Di[wave][lane] = min(max(di, 0), NV - 1);
        }

        // Floyd-Warshall, wave-synchronous, in-place
        #pragma unroll
        for (int k = 0; k < NV; ++k) {
            float t0 = s_dist[wave][i0 * NV + k] + s_dist[wave][k * NV + j0];
            if (t0 < s_dist[wave][c0]) { s_dist[wave][c0] = t0; sp0 += ef0; }
            if (has1) {
                float t1 = s_dist[wave][i1 * NV + k] + s_dist[wave][k * NV + j1];
                if (t1 < s_dist[wave][c1]) { s_dist[wave][c1] = t1; sp1 += ef1; }
            }
        }

        // Integer buckets
        {
            int si = (int)s_dist[wave][c0];
            int ei = (int)sp0;
            s_si[wave][c0] = min(max(si, 0), NV - 1);
            s_ei[wave][c0] = min(max(ei, 0), NV - 1);
        }
        if (has1) {
            int si = (int)s_dist[wave][c1];
            int ei = (int)sp1;
            s_si[wave][c1] = min(max(si, 0), NV - 1);
            s_ei[wave][c1] = min(max(ei, 0), NV - 1);
        }

        // atten_bias = sum_j emb3[Si[i,j]] + emb4[Ei[i,j]]  (per cell (i,cc))
        {
            float acc3 = 0.f, acc4 = 0.f;
            #pragma unroll
            for (int j = 0; j < NV; ++j) {
                acc3 += s_emb3[s_si[wave][i0 * NV + j] * NV + j0];
                acc4 += s_emb4[s_ei[wave][i0 * NV + j] * NV + j0];
            }
            out_atten[g0 + c0] = acc4 + acc3;
        }
        if (has1) {
            float acc3 = 0.f, acc4 = 0.f;
            #pragma unroll
            for (int j = 0; j < NV; ++j) {
                acc3 += s_emb3[s_si[wave][i1 * NV + j] * NV + j1];
                acc4 += s_emb4[s_ei[wave][i1 * NV + j] * NV + j1];
            }
            out_atten[g0 + c1] = acc4 + acc3;
        }
    }

    // ---- Publish s_Di across waves (barrier 2 of 2), then stream 4 slabs ----
    __syncthreads();

    const int ng = min(GPB, BT - gbase);            // graphs in this block
    const size_t slab = (size_t)gbase * (NV * NF);
    const float4* end4 = reinterpret_cast<const float4*>(end_output + slab);
    float4*       out4 = reinterpret_cast<float4*>(out_main + slab);
    const float4* es4  = reinterpret_cast<const float4*>(s_embsum);
    const int items = ng * (NV * NF / 4);           // 640 float4 per graph

    for (int u = tid; u < items; u += 256) {
        int gg  = u / 640;                          // graph within block
        int rem = u - gg * 640;
        int row = rem >> 6;                         // V row
        int f4  = rem & 63;
        float4 e = end4[u];
        float4 s = es4[s_Di[gg][row] * (NF / 4) + f4];
        e.x += s.x; e.y += s.y; e.z += s.z; e.w += s.w;
        out4[u] = e;
    }
}

extern "C" void kernel_launch(void* const* d_in, const int* in_sizes, int n_in,
                              void* d_out, int out_size, void* d_ws, size_t ws_size,
                              hipStream_t stream) {
    const float* end_output = (const float*)d_in[0];
    const float* S          = (const float*)d_in[1];
    const float* mul        = (const float*)d_in[2];
    const float* bias       = (const float*)d_in[3];
    const float* means      = (const float*)d_in[4];
    const float* stds       = (const float*)d_in[5];
    const float* emb_in     = (const float*)d_in[6];
    const float* emb_out    = (const float*)d_in[7];
    const float* emb3       = (const float*)d_in[8];
    const float* emb4       = (const float*)d_in[9];

    float* out_main  = (float*)d_out;
    float* out_atten = out_main + (size_t)in_sizes[0];

    const int BT = in_sizes[1] / (NV * NV);         // 25,600
    const int nblocks = (BT + GPB - 1) / GPB;       // 6,400

    graph_emb_fused<<<nblocks, 256, 0, stream>>>(
        end_output, S, mul, bias, means, stds,
        emb_in, emb_out, emb3, emb4, out_main, out_atten, BT);
}